// Round 1
// baseline (194.553 us; speedup 1.0000x reference)
//
#include <hip/hip_runtime.h>

// Problem constants (from reference setup_inputs)
constexpr int B  = 32;
constexpr int H  = 256;
constexpr int W  = 1216;
constexpr int HW = H * W;            // 311296 (divisible by 4)
constexpr int N  = B * HW;           // 9961472 elements in gt / weight_map
constexpr int NCHUNK  = N / 4;       // 2490368 float4 chunks
constexpr int BLOCKSZ = 256;
// R6 experiment: 2048 blocks = 8 blocks/CU = 32 waves/CU (was 16). Theory:
// the 3.0 TB/s read plateau (R5) is memory-level-parallelism-bound; the fill
// kernel sustains 6.8 TB/s, so HBM itself has headroom. To fit the 64-VGPR
// budget that 8 blocks/CU requires, the pipeline drops to depth-2 and the 8
// counts pack into 4 VGPRs (16-bit halves; max 20 events per half).
constexpr int GRID    = 2048;
constexpr int CSTRIDE = GRID * BLOCKSZ;   // 524288 (NCHUNK/CSTRIDE = 4.75)

// Per-block partials in d_ws: part[block][slot], slot 0..7 = sum(err^2) for
// bin slot+1, slot 8..15 = count for bin slot+1. Plain stores — NO atomics,
// NO fences (R2 lesson: same-address atomics + threadfence cost ~100 us).
constexpr int NSLOT = 16;

// ext_vector types so __builtin_nontemporal_load accepts them
typedef float vfloat4 __attribute__((ext_vector_type(4)));
typedef int   vint4   __attribute__((ext_vector_type(4)));

__device__ __forceinline__ void load3(const float* __restrict__ pred,
                                      const float* __restrict__ gt,
                                      const int*   __restrict__ wm,
                                      int c, vfloat4& p, vfloat4& g, vint4& w)
{
    const int i0 = c * 4;            // flat element index
    const int b  = i0 / HW;          // batch (magic-mul by compiler)
    // nt: R5 showed L1 bypass moved the read plateau 2.44 -> ~3.0 TB/s.
    p = __builtin_nontemporal_load((const vfloat4*)(pred + (i0 + b * HW)));
    g = __builtin_nontemporal_load((const vfloat4*)(gt + i0));
    w = __builtin_nontemporal_load((const vint4*)(wm + i0));
}

// Counts packed: cp[k] holds bin 2k+1 in low 16 bits, bin 2k+2 in high 16.
// Max per-thread events per bin = 5 chunks * 4 elems = 20 << 32768, so the
// halves can never carry into each other.
__device__ __forceinline__ void accum(const vfloat4& p, const vfloat4& g,
                                      const vint4& w, float* sum, int* cp)
{
    const float e0 = p.x - g.x, e1 = p.y - g.y;
    const float e2 = p.z - g.z, e3 = p.w - g.w;
    const float s0 = e0 * e0, s1 = e1 * e1, s2 = e2 * e2, s3 = e3 * e3;
#pragma unroll
    for (int k = 0; k < 4; ++k) {
        const int blo = 2 * k + 1;
        const int bhi = 2 * k + 2;
        sum[2 * k]     += (w.x == blo) ? s0 : 0.f;
        sum[2 * k + 1] += (w.x == bhi) ? s0 : 0.f;
        cp[k] += ((w.x == blo) ? 1 : 0) + ((w.x == bhi) ? 0x10000 : 0);
        sum[2 * k]     += (w.y == blo) ? s1 : 0.f;
        sum[2 * k + 1] += (w.y == bhi) ? s1 : 0.f;
        cp[k] += ((w.y == blo) ? 1 : 0) + ((w.y == bhi) ? 0x10000 : 0);
        sum[2 * k]     += (w.z == blo) ? s2 : 0.f;
        sum[2 * k + 1] += (w.z == bhi) ? s2 : 0.f;
        cp[k] += ((w.z == blo) ? 1 : 0) + ((w.z == bhi) ? 0x10000 : 0);
        sum[2 * k]     += (w.w == blo) ? s3 : 0.f;
        sum[2 * k + 1] += (w.w == bhi) ? s3 : 0.f;
        cp[k] += ((w.w == blo) ? 1 : 0) + ((w.w == bhi) ? 0x10000 : 0);
    }
}

// __launch_bounds__(256, 8): 8 workgroups/CU => VGPR cap 64. Register budget:
// 2 chunks * 12 data VGPRs = 24, 8 sums + 4 packed counts = 12, ~15 addr/misc
// => ~51, fits without spill.
__global__ __launch_bounds__(BLOCKSZ, 8) void seg_mse_kernel(
    const float* __restrict__ pred,
    const float* __restrict__ gt,
    const int*   __restrict__ wm,
    float* __restrict__ part)
{
    float sum[8] = {0.f, 0.f, 0.f, 0.f, 0.f, 0.f, 0.f, 0.f};
    int   cp[4]  = {0, 0, 0, 0};

    const int start = blockIdx.x * BLOCKSZ + threadIdx.x;

    // Depth-2 rotated pipeline: 2 chunk buffers (6 loads = 24 data VGPRs)
    // perpetually outstanding. Every thread has >= 4 chunks (NCHUNK/CSTRIDE
    // = 4.75), so the 2-deep prologue is always in-bounds.
    vfloat4 p0, g0, p1, g1;
    vint4   w0, w1;
    load3(pred, gt, wm, start,           p0, g0, w0);
    load3(pred, gt, wm, start + CSTRIDE, p1, g1, w1);
    int next = start + 2 * CSTRIDE;

    while (true) {
        accum(p0, g0, w0, sum, cp);
        if (next < NCHUNK) { load3(pred, gt, wm, next, p0, g0, w0); next += CSTRIDE; }
        else { accum(p1, g1, w1, sum, cp); break; }

        accum(p1, g1, w1, sum, cp);
        if (next < NCHUNK) { load3(pred, gt, wm, next, p1, g1, w1); next += CSTRIDE; }
        else { accum(p0, g0, w0, sum, cp); break; }
    }

    // wave (64-lane) butterfly reduction: 8 float sums + 4 packed int counts
#pragma unroll
    for (int j = 0; j < 8; ++j) {
#pragma unroll
        for (int off = 32; off > 0; off >>= 1) sum[j] += __shfl_down(sum[j], off);
    }
#pragma unroll
    for (int k = 0; k < 4; ++k) {
#pragma unroll
        for (int off = 32; off > 0; off >>= 1) cp[k] += __shfl_down(cp[k], off);
    }

    // unpack counts (wave totals <= 20*64 = 1280 per half, still no overflow)
    float fcnt[8];
#pragma unroll
    for (int k = 0; k < 4; ++k) {
        fcnt[2 * k]     = (float)(cp[k] & 0xffff);
        fcnt[2 * k + 1] = (float)(cp[k] >> 16);
    }

    // cross-wave reduction in LDS (256 threads = 4 waves)
    __shared__ float lsum[4][8];
    __shared__ float lcnt[4][8];
    const int wave = threadIdx.x >> 6;
    const int lane = threadIdx.x & 63;
    if (lane == 0) {
#pragma unroll
        for (int j = 0; j < 8; ++j) {
            lsum[wave][j] = sum[j];
            lcnt[wave][j] = fcnt[j];
        }
    }
    __syncthreads();

    // 16 plain coalesced stores per block (one 64B segment)
    if (threadIdx.x < 8) {
        const int j = threadIdx.x;
        part[blockIdx.x * NSLOT + j] =
            lsum[0][j] + lsum[1][j] + lsum[2][j] + lsum[3][j];
    } else if (threadIdx.x < 16) {
        const int j = threadIdx.x - 8;
        part[blockIdx.x * NSLOT + 8 + j] =
            lcnt[0][j] + lcnt[1][j] + lcnt[2][j] + lcnt[3][j];
    }
}

// Single-block reduction of GRID x 16 partials (128 KB, L2-resident).
__global__ __launch_bounds__(1024) void finalize_kernel(
    const float* __restrict__ part,
    float* __restrict__ out)
{
    const int tid = threadIdx.x;
    const int j   = tid & 15;        // slot
    const int g   = tid >> 4;        // group 0..63
    float v = 0.f;
#pragma unroll
    for (int i = 0; i < GRID / 64; ++i) {
        v += part[(g + 64 * i) * NSLOT + j];
    }
    // combine groups within the wave: lanes differing in bits 4,5 share slot j
    v += __shfl_xor(v, 16);
    v += __shfl_xor(v, 32);

    // cross-wave: 16 waves each contribute one value per slot
    __shared__ float wsum[16][16];
    const int wave = tid >> 6;
    const int lane = tid & 63;
    if (lane < 16) wsum[wave][lane] = v;
    __syncthreads();

    __shared__ float fin[16];
    if (tid < 16) {
        float t = 0.f;
#pragma unroll
        for (int w = 0; w < 16; ++w) t += wsum[w][tid];
        fin[tid] = t;
    }
    __syncthreads();

    if (tid == 0) {
        float total = 0.f;
#pragma unroll
        for (int j2 = 0; j2 < 8; ++j2) {
            total += fin[j2] / fmaxf(fin[8 + j2], 1.f);
        }
        out[0] = total * (1.f / 8.f);
    }
}

extern "C" void kernel_launch(void* const* d_in, const int* in_sizes, int n_in,
                              void* d_out, int out_size, void* d_ws, size_t ws_size,
                              hipStream_t stream)
{
    const float* pred = (const float*)d_in[0];  // [32,2,256,1216] f32
    const float* gt   = (const float*)d_in[1];  // [32,1,256,1216] f32
    const int*   wm   = (const int*)d_in[2];    // [32,1,256,1216] i32
    float* part = (float*)d_ws;                 // GRID*16 floats = 128 KB

    // No memset needed: every part[] slot is written by the main kernel.
    seg_mse_kernel<<<GRID, BLOCKSZ, 0, stream>>>(pred, gt, wm, part);
    finalize_kernel<<<1, 1024, 0, stream>>>(part, (float*)d_out);
}

// Round 2
// 175.181 us; speedup vs baseline: 1.1106x; 1.1106x over previous
//
#include <hip/hip_runtime.h>
#include <stdint.h>

// Problem constants (from reference setup_inputs)
constexpr int B  = 32;
constexpr int H  = 256;
constexpr int W  = 1216;
constexpr int HW = H * W;              // 311296 (= 1216 * 256, divisible by 256)
constexpr int N  = B * HW;             // 9961472 elements in gt / weight_map
constexpr int WCHUNK  = N / 256;       // 38912 wave-chunks (256 elems = 1KB/stream each)
constexpr int WCPB    = HW / 256;      // 1216 wave-chunks per batch image (exact)
constexpr int BLOCKSZ = 256;           // 4 waves
constexpr int GRID    = 512;           // 2048 waves total; 2 blocks/CU (LDS-bound)
constexpr int NWAVES  = GRID * (BLOCKSZ / 64);      // 2048
constexpr int NITER   = WCHUNK / NWAVES;            // 19 exactly — no bounds checks
constexpr int DEPTH   = 6;             // per-wave LDS ring slots (18 KB/wave in flight)
constexpr int NSLOT   = 16;

// R7 design: the R6 post-mortem showed VGPR_Count=32 every round — the
// allocator refuses to hold a register pipeline, capping per-wave MLP at ~2
// outstanding loads (3.44 TB/s aggregate). Fix: move the in-flight data out
// of VGPRs entirely. Each wave owns a private DEPTH-slot LDS ring filled by
// __builtin_amdgcn_global_load_lds (width=16) and drained with manually
// counted s_waitcnt vmcnt(N) — producer == consumer, so NO s_barrier, no
// cross-wave sync. In-flight bytes/CU = 8 waves * 18 KB = 144 KB >> the
// ~10.6 KB (BW*latency) needed to saturate HBM.

typedef float vfloat4 __attribute__((ext_vector_type(4)));
typedef int   vint4   __attribute__((ext_vector_type(4)));

// Stage one wave-chunk (256 elems, 1 KB/stream) into an LDS slot via DMA.
// LDS dest is wave-uniform base + lane*16 (HW rule); global src is per-lane.
// Our layout is exactly lane-linear, so linear LDS dest matches (m104 rule).
__device__ __forceinline__ void stage_chunk(
    const float* __restrict__ pred, const float* __restrict__ gt,
    const int* __restrict__ wm, int wc, int lane,
    uint8_t* lp, uint8_t* lg, uint8_t* lw)
{
    const int e = wc * 256 + lane * 4;     // element index for this lane
    const int b = wc / WCPB;               // batch (scalar magic-mul)
    __builtin_amdgcn_global_load_lds(
        (const __attribute__((address_space(1))) void*)(pred + e + b * HW),
        (__attribute__((address_space(3))) void*)lp, 16, 0, 0);
    __builtin_amdgcn_global_load_lds(
        (const __attribute__((address_space(1))) void*)(gt + e),
        (__attribute__((address_space(3))) void*)lg, 16, 0, 0);
    __builtin_amdgcn_global_load_lds(
        (const __attribute__((address_space(1))) void*)(wm + e),
        (__attribute__((address_space(3))) void*)lw, 16, 0, 0);
}

__device__ __forceinline__ void accum(const vfloat4& p, const vfloat4& g,
                                      const vint4& w, float* sum, int* cnt)
{
    const float e0 = p.x - g.x, e1 = p.y - g.y;
    const float e2 = p.z - g.z, e3 = p.w - g.w;
    const float s0 = e0 * e0, s1 = e1 * e1, s2 = e2 * e2, s3 = e3 * e3;
#pragma unroll
    for (int j = 0; j < 8; ++j) {
        const int bin = j + 1;
        sum[j] += (w.x == bin) ? s0 : 0.f;
        cnt[j] += (w.x == bin) ? 1 : 0;
        sum[j] += (w.y == bin) ? s1 : 0.f;
        cnt[j] += (w.y == bin) ? 1 : 0;
        sum[j] += (w.z == bin) ? s2 : 0.f;
        cnt[j] += (w.z == bin) ? 1 : 0;
        sum[j] += (w.w == bin) ? s3 : 0.f;
        cnt[j] += (w.w == bin) ? 1 : 0;
    }
}

// LDS cap (72.25 KB/block) limits to 2 blocks/CU; ask for exactly that so the
// VGPR cap is 256 (irrelevant — we only need ~50).
__global__ __launch_bounds__(BLOCKSZ, 2) void seg_mse_kernel(
    const float* __restrict__ pred,
    const float* __restrict__ gt,
    const int*   __restrict__ wm,
    float* __restrict__ part)
{
    // [wave][slot][stream][1KB]
    __shared__ __align__(16) uint8_t lds[4][DEPTH][3][1024];

    float sum[8] = {0.f, 0.f, 0.f, 0.f, 0.f, 0.f, 0.f, 0.f};
    int   cnt[8] = {0, 0, 0, 0, 0, 0, 0, 0};

    const int lane = threadIdx.x & 63;
    const int wave = threadIdx.x >> 6;
    const int gw   = blockIdx.x * 4 + wave;   // global wave id, 0..2047
    const int wc0  = gw * NITER;              // contiguous 19-chunk strip

    // Prologue: fill all DEPTH slots (18 DMA issues, 18 KB in flight).
#pragma unroll
    for (int d = 0; d < DEPTH; ++d)
        stage_chunk(pred, gt, wm, wc0 + d, lane,
                    &lds[wave][d][0][0], &lds[wave][d][1][0], &lds[wave][d][2][0]);

    int slot = 0;
    // Main loop: 13 iterations. Wait for the OLDEST chunk only (5 newer
    // chunks * 3 loads = vmcnt(15) may stay in flight — never drain to 0).
    for (int i = 0; i < NITER - DEPTH; ++i) {
        asm volatile("s_waitcnt vmcnt(15)" ::: "memory");
        const vfloat4 p = *(const vfloat4*)&lds[wave][slot][0][lane * 16];
        const vfloat4 g = *(const vfloat4*)&lds[wave][slot][1][lane * 16];
        const vint4   w = *(const vint4*)&lds[wave][slot][2][lane * 16];
        // ds_reads must complete before the DMA below can overwrite the slot.
        asm volatile("s_waitcnt lgkmcnt(0)" ::: "memory");
        stage_chunk(pred, gt, wm, wc0 + i + DEPTH, lane,
                    &lds[wave][slot][0][0], &lds[wave][slot][1][0], &lds[wave][slot][2][0]);
        accum(p, g, w, sum, cnt);
        slot = (slot == DEPTH - 1) ? 0 : slot + 1;
    }

    // Drain: chunks wc0+13..wc0+18 in slots 1,2,3,4,5,0 with decreasing vmcnt.
#define DRAIN_STEP(VM)                                                        \
    {                                                                         \
        asm volatile("s_waitcnt vmcnt(" #VM ")" ::: "memory");                \
        const vfloat4 p = *(const vfloat4*)&lds[wave][slot][0][lane * 16];    \
        const vfloat4 g = *(const vfloat4*)&lds[wave][slot][1][lane * 16];    \
        const vint4   w = *(const vint4*)&lds[wave][slot][2][lane * 16];      \
        accum(p, g, w, sum, cnt);                                             \
        slot = (slot == DEPTH - 1) ? 0 : slot + 1;                            \
    }
    DRAIN_STEP(15)
    DRAIN_STEP(12)
    DRAIN_STEP(9)
    DRAIN_STEP(6)
    DRAIN_STEP(3)
    DRAIN_STEP(0)
#undef DRAIN_STEP

    // wave (64-lane) butterfly reduction of all 16 partials
    float fcnt[8];
#pragma unroll
    for (int j = 0; j < 8; ++j) fcnt[j] = (float)cnt[j];
#pragma unroll
    for (int j = 0; j < 8; ++j) {
#pragma unroll
        for (int off = 32; off > 0; off >>= 1) {
            sum[j]  += __shfl_down(sum[j], off);
            fcnt[j] += __shfl_down(fcnt[j], off);
        }
    }

    // cross-wave reduction in LDS (4 waves)
    __shared__ float lsum[4][8];
    __shared__ float lcnt[4][8];
    if (lane == 0) {
#pragma unroll
        for (int j = 0; j < 8; ++j) {
            lsum[wave][j] = sum[j];
            lcnt[wave][j] = fcnt[j];
        }
    }
    __syncthreads();

    // 16 plain coalesced stores per block (one 64B segment)
    if (threadIdx.x < 8) {
        const int j = threadIdx.x;
        part[blockIdx.x * NSLOT + j] =
            lsum[0][j] + lsum[1][j] + lsum[2][j] + lsum[3][j];
    } else if (threadIdx.x < 16) {
        const int j = threadIdx.x - 8;
        part[blockIdx.x * NSLOT + 8 + j] =
            lcnt[0][j] + lcnt[1][j] + lcnt[2][j] + lcnt[3][j];
    }
}

// Single-block reduction of GRID x 16 partials (32 KB, L2-resident).
__global__ __launch_bounds__(1024) void finalize_kernel(
    const float* __restrict__ part,
    float* __restrict__ out)
{
    const int tid = threadIdx.x;
    const int j   = tid & 15;        // slot
    const int g   = tid >> 4;        // group 0..63
    float v = 0.f;
#pragma unroll
    for (int i = 0; i < GRID / 64; ++i) {
        v += part[(g + 64 * i) * NSLOT + j];
    }
    // combine groups within the wave: lanes differing in bits 4,5 share slot j
    v += __shfl_xor(v, 16);
    v += __shfl_xor(v, 32);

    // cross-wave: 16 waves each contribute one value per slot
    __shared__ float wsum[16][16];
    const int wave = tid >> 6;
    const int lane = tid & 63;
    if (lane < 16) wsum[wave][lane] = v;
    __syncthreads();

    __shared__ float fin[16];
    if (tid < 16) {
        float t = 0.f;
#pragma unroll
        for (int w = 0; w < 16; ++w) t += wsum[w][tid];
        fin[tid] = t;
    }
    __syncthreads();

    if (tid == 0) {
        float total = 0.f;
#pragma unroll
        for (int j2 = 0; j2 < 8; ++j2) {
            total += fin[j2] / fmaxf(fin[8 + j2], 1.f);
        }
        out[0] = total * (1.f / 8.f);
    }
}

extern "C" void kernel_launch(void* const* d_in, const int* in_sizes, int n_in,
                              void* d_out, int out_size, void* d_ws, size_t ws_size,
                              hipStream_t stream)
{
    const float* pred = (const float*)d_in[0];  // [32,2,256,1216] f32
    const float* gt   = (const float*)d_in[1];  // [32,1,256,1216] f32
    const int*   wm   = (const int*)d_in[2];    // [32,1,256,1216] i32
    float* part = (float*)d_ws;                 // GRID*16 floats = 32 KB

    // No memset needed: every part[] slot is written by the main kernel.
    seg_mse_kernel<<<GRID, BLOCKSZ, 0, stream>>>(pred, gt, wm, part);
    finalize_kernel<<<1, 1024, 0, stream>>>(part, (float*)d_out);
}

// Round 6
// 170.336 us; speedup vs baseline: 1.1422x; 1.0284x over previous
//
#include <hip/hip_runtime.h>

// Problem constants (from reference setup_inputs)
constexpr int B  = 32;
constexpr int H  = 256;
constexpr int W  = 1216;
constexpr int HW = H * W;            // 311296 (divisible by 4)
constexpr int N  = B * HW;           // 9961472 elements in gt / weight_map
constexpr int NCHUNK  = N / 4;       // 2490368 float4 chunks
constexpr int BLOCKSZ = 256;
constexpr int GRID    = 1024;        // 4 blocks/CU; 9.5 chunks/thread (steady state)
constexpr int CSTRIDE = GRID * BLOCKSZ;   // 262144
constexpr int NSLOT   = 16;

// R11: revert to the verified R0 compiler-path kernel (47us seg, passed).
// The hand-asm pipeline (R8-R10) is abandoned: SIGABRT once, corrupted twice
// with the same absmax class even after full sched_barrier bracketing —
// unobservable backend interaction, not worth a 4th blind round.
// Single change vs R0: DROP the nontemporal flag. The harness's fill
// kernels rewrite all inputs (637 MB writes/iter @ 6.8 TB/s) immediately
// before seg, so a large fraction of the 119.5 MB input set is L2/L3-dirty.
// nt (SLC) forces those reads to HBM anyway: R1-with-nt fetched 102 MB of
// 119.5 unique (15% cache hit); R2-without fetched 58 MB (51% hit). Plain
// cached loads let L2/L3 serve the warm lines at cache BW.

typedef float vfloat4 __attribute__((ext_vector_type(4)));
typedef int   vint4   __attribute__((ext_vector_type(4)));

__device__ __forceinline__ void load3(const float* __restrict__ pred,
                                      const float* __restrict__ gt,
                                      const int*   __restrict__ wm,
                                      int c, vfloat4& p, vfloat4& g, vint4& w)
{
    const int i0 = c * 4;            // flat element index
    const int b  = i0 / HW;          // batch (magic-mul by compiler)
    p = *(const vfloat4*)(pred + (i0 + b * HW));
    g = *(const vfloat4*)(gt + i0);
    w = *(const vint4*)(wm + i0);
}

__device__ __forceinline__ void accum(const vfloat4& p, const vfloat4& g,
                                      const vint4& w, float* sum, int* cnt)
{
    const float e0 = p.x - g.x, e1 = p.y - g.y;
    const float e2 = p.z - g.z, e3 = p.w - g.w;
    const float s0 = e0 * e0, s1 = e1 * e1, s2 = e2 * e2, s3 = e3 * e3;
#pragma unroll
    for (int j = 0; j < 8; ++j) {
        const int bin = j + 1;
        sum[j] += (w.x == bin) ? s0 : 0.f;
        cnt[j] += (w.x == bin) ? 1 : 0;
        sum[j] += (w.y == bin) ? s1 : 0.f;
        cnt[j] += (w.y == bin) ? 1 : 0;
        sum[j] += (w.z == bin) ? s2 : 0.f;
        cnt[j] += (w.z == bin) ? 1 : 0;
        sum[j] += (w.w == bin) ? s3 : 0.f;
        cnt[j] += (w.w == bin) ? 1 : 0;
    }
}

__global__ __launch_bounds__(BLOCKSZ, 4) void seg_mse_kernel(
    const float* __restrict__ pred,
    const float* __restrict__ gt,
    const int*   __restrict__ wm,
    float* __restrict__ part)
{
    float sum[8] = {0.f, 0.f, 0.f, 0.f, 0.f, 0.f, 0.f, 0.f};
    int   cnt[8] = {0, 0, 0, 0, 0, 0, 0, 0};

    const int start = blockIdx.x * BLOCKSZ + threadIdx.x;

    // Depth-3 rotated pipeline: 3 chunk buffers (9 loads) outstanding as far
    // as the allocator allows. Every thread has >= 9 chunks (NCHUNK/CSTRIDE
    // = 9.5), so the 3-deep prologue is always in-bounds.
    vfloat4 p0, g0, p1, g1, p2, g2;
    vint4   w0, w1, w2;
    load3(pred, gt, wm, start,               p0, g0, w0);
    load3(pred, gt, wm, start + CSTRIDE,     p1, g1, w1);
    load3(pred, gt, wm, start + 2 * CSTRIDE, p2, g2, w2);
    int next = start + 3 * CSTRIDE;

    while (true) {
        accum(p0, g0, w0, sum, cnt);
        if (next < NCHUNK) { load3(pred, gt, wm, next, p0, g0, w0); next += CSTRIDE; }
        else { accum(p1, g1, w1, sum, cnt); accum(p2, g2, w2, sum, cnt); break; }

        accum(p1, g1, w1, sum, cnt);
        if (next < NCHUNK) { load3(pred, gt, wm, next, p1, g1, w1); next += CSTRIDE; }
        else { accum(p2, g2, w2, sum, cnt); accum(p0, g0, w0, sum, cnt); break; }

        accum(p2, g2, w2, sum, cnt);
        if (next < NCHUNK) { load3(pred, gt, wm, next, p2, g2, w2); next += CSTRIDE; }
        else { accum(p0, g0, w0, sum, cnt); accum(p1, g1, w1, sum, cnt); break; }
    }

    // wave (64-lane) butterfly reduction of all 16 partials
    float fcnt[8];
#pragma unroll
    for (int j = 0; j < 8; ++j) fcnt[j] = (float)cnt[j];
#pragma unroll
    for (int j = 0; j < 8; ++j) {
#pragma unroll
        for (int off = 32; off > 0; off >>= 1) {
            sum[j]  += __shfl_down(sum[j], off);
            fcnt[j] += __shfl_down(fcnt[j], off);
        }
    }

    // cross-wave reduction in LDS (256 threads = 4 waves)
    __shared__ float lsum[4][8];
    __shared__ float lcnt[4][8];
    const int wave = threadIdx.x >> 6;
    const int lane = threadIdx.x & 63;
    if (lane == 0) {
#pragma unroll
        for (int j = 0; j < 8; ++j) {
            lsum[wave][j] = sum[j];
            lcnt[wave][j] = fcnt[j];
        }
    }
    __syncthreads();

    // 16 plain coalesced stores per block (one 64B segment)
    if (threadIdx.x < 8) {
        const int j = threadIdx.x;
        part[blockIdx.x * NSLOT + j] =
            lsum[0][j] + lsum[1][j] + lsum[2][j] + lsum[3][j];
    } else if (threadIdx.x < 16) {
        const int j = threadIdx.x - 8;
        part[blockIdx.x * NSLOT + 8 + j] =
            lcnt[0][j] + lcnt[1][j] + lcnt[2][j] + lcnt[3][j];
    }
}

// Single-block reduction of GRID x 16 partials (64 KB, L2-resident).
__global__ __launch_bounds__(1024) void finalize_kernel(
    const float* __restrict__ part,
    float* __restrict__ out)
{
    const int tid = threadIdx.x;
    const int j   = tid & 15;        // slot
    const int g   = tid >> 4;        // group 0..63
    float v = 0.f;
#pragma unroll
    for (int i = 0; i < GRID / 64; ++i) {
        v += part[(g + 64 * i) * NSLOT + j];
    }
    // combine groups within the wave: lanes differing in bits 4,5 share slot j
    v += __shfl_xor(v, 16);
    v += __shfl_xor(v, 32);

    // cross-wave: 16 waves each contribute one value per slot
    __shared__ float wsum[16][16];
    const int wave = tid >> 6;
    const int lane = tid & 63;
    if (lane < 16) wsum[wave][lane] = v;
    __syncthreads();

    __shared__ float fin[16];
    if (tid < 16) {
        float t = 0.f;
#pragma unroll
        for (int w = 0; w < 16; ++w) t += wsum[w][tid];
        fin[tid] = t;
    }
    __syncthreads();

    if (tid == 0) {
        float total = 0.f;
#pragma unroll
        for (int j2 = 0; j2 < 8; ++j2) {
            total += fin[j2] / fmaxf(fin[8 + j2], 1.f);
        }
        out[0] = total * (1.f / 8.f);
    }
}

extern "C" void kernel_launch(void* const* d_in, const int* in_sizes, int n_in,
                              void* d_out, int out_size, void* d_ws, size_t ws_size,
                              hipStream_t stream)
{
    const float* pred = (const float*)d_in[0];  // [32,2,256,1216] f32
    const float* gt   = (const float*)d_in[1];  // [32,1,256,1216] f32
    const int*   wm   = (const int*)d_in[2];    // [32,1,256,1216] i32
    float* part = (float*)d_ws;                 // GRID*16 floats = 64 KB

    // No memset needed: every part[] slot is written by the main kernel.
    seg_mse_kernel<<<GRID, BLOCKSZ, 0, stream>>>(pred, gt, wm, part);
    finalize_kernel<<<1, 1024, 0, stream>>>(part, (float*)d_out);
}